// Round 10
// baseline (313.597 us; speedup 1.0000x reference)
//
#include <hip/hip_runtime.h>
#include <cfloat>
#include <stdint.h>

// VQ argmin via exact-split f16 MFMA GEMM — R30: revert to the verified best
// (R28: separate extract, no done-counter — R29's fold cost +16us via per-block
// end-of-kernel coherence round-trips; second confirmation after R24 that
// global handshakes in bulk-kernel tails are net-negative) + T5 s_setprio
// around the MFMA clusters. Mechanism: the K-loop is barrier-free, so the 16
// waves/CU drift to independent phases (attn-like, m191 +4-7%), giving the CU
// scheduler MFMA-ready vs load-issuing waves to arbitrate; setprio(1) keeps
// the matrix pipe fed. Gemm otherwise R27/R28-verbatim (128x128 block, 2x2
// waves of 64x64, direct-global, T1/T3/T2 prefetch ping-pong, 64 VGPR +
// 64 AGPR = 4 blocks/CU). Numerics bit-identical to all passers; atomicMin ==
// sequential u64-min (ties impossible since k differs).
#define KC 8192
#define NQ 8192
#define DD 256
#define NSTAGE 8
#define BP_PAD 2              // LDS row stride 258 f16: phase-2 bank-conflict-free

typedef _Float16 f16;
typedef _Float16 half8 __attribute__((ext_vector_type(8)));
typedef float floatx4 __attribute__((ext_vector_type(4)));

// ---- workspace maps ----
#define WS_AH   0
#define WS_AL   4194304
#define WS_BH   8388608
#define WS_BL1  12582912           // 1-pass: Bh/Bl 4MB each
#define WS_KEY1 16777216
#define WS_NEED1 (16777216ull + 65536ull)   // 16.06 MiB (<= every observed ws)
#define WS_BL2  10485760           // 2-pass fallback: Bh/Bl 2MB each
#define WS_KEY2 12582912

// ---- device helpers ----
// B-prep (R28 coalesced LDS transpose; output bit-identical to the verified
// [ntl][s 8][q 4][n 128] granule layout). Block = 32 codes (c0 = blk*32).
__device__ __forceinline__ void prep_b_coal(const float* __restrict__ cb,
                                            f16* __restrict__ Bh, f16* __restrict__ Bl,
                                            int kofs, int blk, int tid,
                                            f16 (*Lh)[DD + BP_PAD], f16 (*Ll)[DD + BP_PAD]) {
    const int c0 = blk * 32;
    const int r = tid >> 3;
    const int j = tid & 7;
    const float* rowp = cb + (size_t)(kofs + c0 + r) * DD + j * 4;
    #pragma unroll
    for (int rr = 0; rr < 8; ++rr) {
        const float4 v = *(const float4*)(rowp + rr * 32);
        float vv[4] = {v.x, v.y, v.z, v.w};
        const int d0 = rr * 32 + j * 4;
        #pragma unroll
        for (int i = 0; i < 4; ++i) {
            float e = vv[i] * 8192.0f;               // exact pow2 scale
            f16 h = (f16)e;
            Lh[r][d0 + i] = h;
            Ll[r][d0 + i] = (f16)(e - (float)h);     // exact fp32 residual
        }
    }
    __syncthreads();
    const int nn = tid & 31;
    const int sq8 = tid >> 5;                        // 0..7
    const int ntl_l = blk >> 2;                      // local ntl within this pass
    const int n0 = (blk & 3) * 32;
    #pragma unroll
    for (int rr = 0; rr < 4; ++rr) {
        const int sq = rr * 8 + sq8;                 // 0..31
        const int s = sq >> 2, q = sq & 3;
        const int d0 = s * 32 + q * 8;
        half8 h8, l8;
        #pragma unroll
        for (int i = 0; i < 8; ++i) { h8[i] = Lh[nn][d0 + i]; l8[i] = Ll[nn][d0 + i]; }
        const size_t og = ((size_t)(ntl_l * 8 + s) * 4 + q) * 128 + n0 + nn;
        *(half8*)(Bh + og * 8) = h8;                 // 32-lane 512B coalesced run
        *(half8*)(Bl + og * 8) = l8;
    }
}

// A-prep (verified R4..R28 layout, byte-identical granules):
//   gid = ((mt*8+st)*4+q)*256 + r holds z[d=st*32+q*8+j][Q=mt*256+r] hi/lo.
__device__ __forceinline__ void prep_a_vec_body(const float* __restrict__ z,
                                                f16* __restrict__ Ah, f16* __restrict__ Al,
                                                int bid, int tid) {
    const int mt = bid >> 3;
    const int s  = bid & 7;
    const int q  = tid >> 6;
    const int lane = tid & 63;
    const int r0 = lane * 4;
    const int Q0 = mt * 256;
    const int b = Q0 >> 10;
    const int t0 = (Q0 & 1023) + r0;
    const float* zp = z + (size_t)b * (DD * 1024) + t0;
    const int d0 = s * 32 + q * 8;
    float4 v[8];
    #pragma unroll
    for (int j = 0; j < 8; ++j)
        v[j] = *(const float4*)(zp + (size_t)(d0 + j) * 1024);
    const size_t gbase = (((size_t)(mt * 8 + s) * 4 + q) * 256 + r0);
    #pragma unroll
    for (int dq = 0; dq < 4; ++dq) {
        half8 zh8, zl8;
        #pragma unroll
        for (int j = 0; j < 8; ++j) {
            float vv = (dq == 0) ? v[j].x : (dq == 1) ? v[j].y : (dq == 2) ? v[j].z : v[j].w;
            f16 h = (f16)vv;
            zh8[j] = h;
            zl8[j] = (f16)(vv - (float)h);       // exact fp32 residual
        }
        *(half8*)(Ah + (gbase + dq) * 8) = zh8;
        *(half8*)(Al + (gbase + dq) * 8) = zl8;
    }
}

// zsq split across 2 threads/query (exact partial chains of all passers;
// zsq[q] = s0 + s1 identical). Also inits the atomic key array.
__device__ __forceinline__ void zsq2_body(const float* __restrict__ z,
                                          float* __restrict__ zsq,
                                          unsigned long long* __restrict__ key,
                                          int gid) {
    int q = gid >> 1, half = gid & 1;
    int b = q >> 10, t = q & 1023;
    const float* p = z + (size_t)b * (DD * 1024) + t + (size_t)(half * 128) * 1024;
    float s = 0.f;
    #pragma unroll 8
    for (int d = 0; d < 128; ++d) { float v = p[(size_t)d * 1024]; s = fmaf(v, v, s); }
    float so = __shfl_xor(s, 1, 64);             // partner half, same q
    if (half == 0) { zsq[q] = s + so; key[q] = ~0ull; }
}

// ---- fused prep: blocks [0,64) zsq+key | [64,320) B-coal | [320,576) A ----
__global__ void vq_prep_all(const float* __restrict__ z, const float* __restrict__ cb,
                            f16* __restrict__ Ah, f16* __restrict__ Al,
                            f16* __restrict__ Bh, f16* __restrict__ Bl,
                            float* __restrict__ zsq, unsigned long long* __restrict__ key) {
    __shared__ f16 Lh[32][DD + BP_PAD];
    __shared__ f16 Ll[32][DD + BP_PAD];
    int bid = blockIdx.x;
    int tid = threadIdx.x;
    if (bid < 64) {
        zsq2_body(z, zsq, key, bid * 256 + tid);
    } else if (bid < 320) {
        prep_b_coal(cb, Bh, Bl, 0, bid - 64, tid, Lh, Ll);
    } else {
        prep_a_vec_body(z, Ah, Al, bid - 320, tid);
    }
}

// standalone preps for the 2-pass fallback
__global__ void vq_prep_az(const float* __restrict__ z,
                           f16* __restrict__ Ah, f16* __restrict__ Al,
                           float* __restrict__ zsq, unsigned long long* __restrict__ key) {
    int bid = blockIdx.x;
    if (bid < 64) zsq2_body(z, zsq, key, bid * 256 + threadIdx.x);
    else          prep_a_vec_body(z, Ah, Al, bid - 64, threadIdx.x);
}
__global__ void vq_prep_b(const float* __restrict__ cb,
                          f16* __restrict__ Bh, f16* __restrict__ Bl, int kofs) {
    __shared__ f16 Lh[32][DD + BP_PAD];
    __shared__ f16 Ll[32][DD + BP_PAD];
    prep_b_coal(cb, Bh, Bl, kofs, blockIdx.x, threadIdx.x, Lh, Ll);
}

// 16 MFMAs of one term over the 4x4 accumulator tile
#define TERM16(AF, BF) do {                                                     \
    _Pragma("unroll") for (int _m = 0; _m < 4; ++_m)                            \
      _Pragma("unroll") for (int _n = 0; _n < 4; ++_n)                          \
        acc[_m][_n] = __builtin_amdgcn_mfma_f32_16x16x32_f16(                   \
            AF[_m], BF[_n], acc[_m][_n], 0, 0, 0);                              \
} while (0)

#define PRIO1 __builtin_amdgcn_s_setprio(1)
#define PRIO0 __builtin_amdgcn_s_setprio(0)

// ---- main GEMM (R28 body + T5 setprio): 128x128 block, 2x2 waves of 64x64,
//      direct-global, no K-loop barriers, T1/T3/T2 prefetch ping-pong, live
//      fragments fixed at 16 x half8 (64 VGPR + 64 AGPR). setprio(1) around
//      MFMA clusters: waves drift to independent phases (barrier-free), so
//      the CU scheduler favors MFMA-ready waves over load-issuing ones. ----
__global__ __launch_bounds__(256, 4)
void vq_gemm16(const f16* __restrict__ Ah, const f16* __restrict__ Al,
               const f16* __restrict__ Bh, const f16* __restrict__ Bl,
               const float* __restrict__ zsq, unsigned long long* __restrict__ keyp,
               int kofs) {
    // Swizzle (R12/R21-verified): per XCD, 8-ntl B chunks x 8 mh2 A tiles.
    const int flat = blockIdx.x;
    const int xcd = flat & 7;
    const int idx = flat >> 3;
    const int mh2 = xcd * 8 + ((idx >> 3) & 7);     // 0..63, 128-row tile
    const int ntl = (idx >> 6) * 8 + (idx & 7);     // 0..63 / 0..31
    const int tid = threadIdx.x;
    const int lane = tid & 63;
    const int wv = tid >> 6;
    const int wm = wv >> 1, wn = wv & 1;            // 2x2 waves of 64x64
    const int quad = lane >> 4;
    const int l16 = lane & 15;

    __shared__ unsigned long long kbuf[256];        // epilogue merge only

    floatx4 acc[4][4];
    #pragma unroll
    for (int i = 0; i < 4; ++i)
        #pragma unroll
        for (int j = 0; j < 4; ++j) acc[i][j] = (floatx4)0.f;

    const int mt = mh2 >> 1;
    const int r0 = (mh2 & 1) * 128;
    // A fragment address in halfs (byte-identical granules to all passers):
    const size_t abase = ((((size_t)(mt * 8) * 4) + quad) * 256
                          + (size_t)(r0 + wm * 64 + l16)) * 8;
    const f16* Ap  = Ah + abase;
    const f16* Alp = Al + abase;
    const f16* Bpb = Bh + ((size_t)(ntl * 8) * 4 + quad) * 1024 + (size_t)(wn * 64 + l16) * 8;
    const f16* Blb = Bl + ((size_t)(ntl * 8) * 4 + quad) * 1024 + (size_t)(wn * 64 + l16) * 8;

    // Fragment slots: A0/A1 (A-side), B0/B1 (B-side). Even stage roles:
    // av=A0, aw=A1, bh=B0, bl=B1; odd stage: av=A1, aw=A0, bh=B0, bl=B1.
    half8 A0[4], A1[4], B0[4], B1[4];
    #pragma unroll
    for (int i = 0; i < 4; ++i) {
        A0[i] = *(const half8*)(Ap  + (size_t)i * 128);   // av(0)
        A1[i] = *(const half8*)(Alp + (size_t)i * 128);   // aw(0)
        B0[i] = *(const half8*)(Bpb + i * 128);           // bh(0)
        B1[i] = *(const half8*)(Blb + i * 128);           // bl(0)
    }

    #pragma unroll
    for (int su = 0; su < 4; ++su) {
        // ================= even stage s = 2*su =================
        PRIO1;
        TERM16(A0, B0);                              // T1: av*bh
        TERM16(A1, B0);                              // T3: aw*bh  (frees A1,B0)
        PRIO0;
        #pragma unroll
        for (int i = 0; i < 4; ++i) {                // prefetch av',bh'
            A1[i] = *(const half8*)(Ap  + 8192 + (size_t)i * 128);
            B0[i] = *(const half8*)(Bpb + 4096 + i * 128);
        }
        PRIO1;
        TERM16(A0, B1);                              // T2: av*bl  (frees A0,B1)
        PRIO0;
        #pragma unroll
        for (int i = 0; i < 4; ++i) {                // prefetch aw',bl'
            A0[i] = *(const half8*)(Alp + 8192 + (size_t)i * 128);
            B1[i] = *(const half8*)(Blb + 4096 + i * 128);
        }
        // ================= odd stage s = 2*su+1 (roles swapped) =================
        PRIO1;
        TERM16(A1, B0);                              // T1: av'*bh'
        TERM16(A0, B0);                              // T3: aw'*bh' (frees A0,B0)
        PRIO0;
        if (su < 3) {
            #pragma unroll
            for (int i = 0; i < 4; ++i) {            // prefetch av'',bh''
                A0[i] = *(const half8*)(Ap  + 16384 + (size_t)i * 128);
                B0[i] = *(const half8*)(Bpb + 8192 + i * 128);
            }
        }
        PRIO1;
        TERM16(A1, B1);                              // T2: av'*bl' (frees A1,B1)
        PRIO0;
        if (su < 3) {
            #pragma unroll
            for (int i = 0; i < 4; ++i) {            // prefetch aw'',bl''
                A1[i] = *(const half8*)(Alp + 16384 + (size_t)i * 128);
                B1[i] = *(const half8*)(Blb + 8192 + i * 128);
            }
            // advance two stages
            Ap += 16384; Alp += 16384; Bpb += 8192; Blb += 8192;
        }
    }

    // ---- epilogue (verified C/D map): dist quantization + 2-way merge +
    //      device-wide atomicMin (== sequential u64-min; ties impossible) ----
    const int kb = kofs + ntl * 128 + wn * 64;
    #pragma unroll
    for (int mi = 0; mi < 4; ++mi) {
        #pragma unroll
        for (int reg = 0; reg < 4; ++reg) {
            int qlocal = wm * 64 + mi * 16 + quad * 4 + reg;   // verified map
            float zq = zsq[mh2 * 128 + qlocal];
            float bd = FLT_MAX; int bk = 0;
            #pragma unroll
            for (int nj = 0; nj < 4; ++nj) {        // ascending k: '<' keeps lowest
                float dd = zq - acc[mi][nj][reg] * 0x1p-12f;  // single fp32 rounding
                int kk = kb + nj * 16 + l16;
                if (dd < bd || (dd == bd && kk < bk)) { bd = dd; bk = kk; }
            }
            #pragma unroll
            for (int mm = 1; mm <= 8; mm <<= 1) {   // 16-lane butterfly, same q
                float od = __shfl_xor(bd, mm, 64);
                int ok = __shfl_xor(bk, mm, 64);
                if (od < bd || (od == bd && ok < bk)) { bd = od; bk = ok; }
            }
            if (l16 == 0)
                kbuf[wn * 128 + qlocal] =
                    ((unsigned long long)__float_as_uint(bd) << 32) | (unsigned int)bk;
        }
    }
    __syncthreads();
    if (tid < 128) {
        unsigned long long k0 = kbuf[tid];
        unsigned long long k1 = kbuf[128 + tid];
        unsigned long long key = (k1 < k0) ? k1 : k0;
        atomicMin(&keyp[mh2 * 128 + tid], key);     // fire-and-forget, no fence
    }
}

__global__ void vq_extract(const unsigned long long* __restrict__ key,
                           int* __restrict__ out) {
    int q = blockIdx.x * 256 + threadIdx.x;
    out[q] = (int)(key[q] & 0xFFFFFFFFull);
}

extern "C" void kernel_launch(void* const* d_in, const int* in_sizes, int n_in,
                              void* d_out, int out_size, void* d_ws, size_t ws_size,
                              hipStream_t stream) {
    const float* z  = (const float*)d_in[0];   // (8, 256, 1024) fp32
    const float* cb = (const float*)d_in[1];   // (8192, 256) fp32
    char* ws = (char*)d_ws;
    f16* Ah = (f16*)(ws + WS_AH);
    f16* Al = (f16*)(ws + WS_AL);
    // zsq parked in d_out (32 KB): read by gemm, overwritten by extract.
    float* zsq = (float*)d_out;
    int* out = (int*)d_out;

    if (ws_size >= WS_NEED1) {
        f16* Bh = (f16*)(ws + WS_BH);
        f16* Bl = (f16*)(ws + WS_BL1);
        unsigned long long* key = (unsigned long long*)(ws + WS_KEY1);
        vq_prep_all<<<576, 256, 0, stream>>>(z, cb, Ah, Al, Bh, Bl, zsq, key);
        vq_gemm16<<<4096, 256, 0, stream>>>(Ah, Al, Bh, Bl, zsq, key, 0);
        vq_extract<<<NQ / 256, 256, 0, stream>>>(key, out);
    } else {
        // 2-pass fallback (12.06 MB): B buffer reused across halves of K.
        f16* Bh = (f16*)(ws + WS_BH);
        f16* Bl = (f16*)(ws + WS_BL2);
        unsigned long long* key = (unsigned long long*)(ws + WS_KEY2);
        vq_prep_az<<<320, 256, 0, stream>>>(z, Ah, Al, zsq, key);
        for (int p = 0; p < 2; ++p) {
            int kofs = p * 4096;
            vq_prep_b<<<128, 256, 0, stream>>>(cb, Bh, Bl, kofs);
            vq_gemm16<<<2048, 256, 0, stream>>>(Ah, Al, Bh, Bl, zsq, key, kofs);
        }
        vq_extract<<<NQ / 256, 256, 0, stream>>>(key, out);
    }
}

// Round 11
// 186.462 us; speedup vs baseline: 1.6818x; 1.6818x over previous
//
#include <hip/hip_runtime.h>
#include <cfloat>
#include <stdint.h>

// VQ argmin via exact-split f16 MFMA GEMM — R31 = R28 verbatim (final revert).
// R30's setprio was toxic: the builtins fenced the scheduler, live-ranges
// collapsed onto the 128-reg cap, and the compiler spilled to scratch
// (WRITE_SIZE 4MB -> 300MB of HBM spill traffic; gemm 271us). Lesson: in a
// register-saturated kernel, scheduling-fence intrinsics convert to spills —
// diagnose via WRITE_SIZE, not VGPR_Count (which shows the capped alloc).
// Session floor: gemm 120.5us / 854 TF / MfmaUtil 38% (8 structural attacks
// all neutral-to-negative: LDS-staged, barrier-free, 8-phase 256^2, 128x64
// tile, fence-fold, 32x32 shape, explicit pipeline, setprio); rest ~65us of
// fixed harness overhead (insensitive to 4 prep restructures, 2 fold attempts).
// Numerics bit-identical to all passers: 3-term split zh*eh+zh*el+zl*eh with
// e'=e*2^13, dist=fp32(zsq-acc*2^-12), u64 atomicMin (ties impossible).
#define KC 8192
#define NQ 8192
#define DD 256
#define NSTAGE 8
#define BP_PAD 2              // LDS row stride 258 f16: phase-2 bank-conflict-free

typedef _Float16 f16;
typedef _Float16 half8 __attribute__((ext_vector_type(8)));
typedef float floatx4 __attribute__((ext_vector_type(4)));

// ---- workspace maps ----
#define WS_AH   0
#define WS_AL   4194304
#define WS_BH   8388608
#define WS_BL1  12582912           // 1-pass: Bh/Bl 4MB each
#define WS_KEY1 16777216
#define WS_NEED1 (16777216ull + 65536ull)   // 16.06 MiB (<= every observed ws)
#define WS_BL2  10485760           // 2-pass fallback: Bh/Bl 2MB each
#define WS_KEY2 12582912

// ---- device helpers ----
// B-prep (R28 coalesced LDS transpose; output bit-identical to the verified
// [ntl][s 8][q 4][n 128] granule layout). Block = 32 codes (c0 = blk*32).
__device__ __forceinline__ void prep_b_coal(const float* __restrict__ cb,
                                            f16* __restrict__ Bh, f16* __restrict__ Bl,
                                            int kofs, int blk, int tid,
                                            f16 (*Lh)[DD + BP_PAD], f16 (*Ll)[DD + BP_PAD]) {
    const int c0 = blk * 32;
    const int r = tid >> 3;
    const int j = tid & 7;
    const float* rowp = cb + (size_t)(kofs + c0 + r) * DD + j * 4;
    #pragma unroll
    for (int rr = 0; rr < 8; ++rr) {
        const float4 v = *(const float4*)(rowp + rr * 32);
        float vv[4] = {v.x, v.y, v.z, v.w};
        const int d0 = rr * 32 + j * 4;
        #pragma unroll
        for (int i = 0; i < 4; ++i) {
            float e = vv[i] * 8192.0f;               // exact pow2 scale
            f16 h = (f16)e;
            Lh[r][d0 + i] = h;
            Ll[r][d0 + i] = (f16)(e - (float)h);     // exact fp32 residual
        }
    }
    __syncthreads();
    const int nn = tid & 31;
    const int sq8 = tid >> 5;                        // 0..7
    const int ntl_l = blk >> 2;                      // local ntl within this pass
    const int n0 = (blk & 3) * 32;
    #pragma unroll
    for (int rr = 0; rr < 4; ++rr) {
        const int sq = rr * 8 + sq8;                 // 0..31
        const int s = sq >> 2, q = sq & 3;
        const int d0 = s * 32 + q * 8;
        half8 h8, l8;
        #pragma unroll
        for (int i = 0; i < 8; ++i) { h8[i] = Lh[nn][d0 + i]; l8[i] = Ll[nn][d0 + i]; }
        const size_t og = ((size_t)(ntl_l * 8 + s) * 4 + q) * 128 + n0 + nn;
        *(half8*)(Bh + og * 8) = h8;                 // 32-lane 512B coalesced run
        *(half8*)(Bl + og * 8) = l8;
    }
}

// A-prep (verified R4..R28 layout, byte-identical granules):
//   gid = ((mt*8+st)*4+q)*256 + r holds z[d=st*32+q*8+j][Q=mt*256+r] hi/lo.
__device__ __forceinline__ void prep_a_vec_body(const float* __restrict__ z,
                                                f16* __restrict__ Ah, f16* __restrict__ Al,
                                                int bid, int tid) {
    const int mt = bid >> 3;
    const int s  = bid & 7;
    const int q  = tid >> 6;
    const int lane = tid & 63;
    const int r0 = lane * 4;
    const int Q0 = mt * 256;
    const int b = Q0 >> 10;
    const int t0 = (Q0 & 1023) + r0;
    const float* zp = z + (size_t)b * (DD * 1024) + t0;
    const int d0 = s * 32 + q * 8;
    float4 v[8];
    #pragma unroll
    for (int j = 0; j < 8; ++j)
        v[j] = *(const float4*)(zp + (size_t)(d0 + j) * 1024);
    const size_t gbase = (((size_t)(mt * 8 + s) * 4 + q) * 256 + r0);
    #pragma unroll
    for (int dq = 0; dq < 4; ++dq) {
        half8 zh8, zl8;
        #pragma unroll
        for (int j = 0; j < 8; ++j) {
            float vv = (dq == 0) ? v[j].x : (dq == 1) ? v[j].y : (dq == 2) ? v[j].z : v[j].w;
            f16 h = (f16)vv;
            zh8[j] = h;
            zl8[j] = (f16)(vv - (float)h);       // exact fp32 residual
        }
        *(half8*)(Ah + (gbase + dq) * 8) = zh8;
        *(half8*)(Al + (gbase + dq) * 8) = zl8;
    }
}

// zsq split across 2 threads/query (exact partial chains of all passers;
// zsq[q] = s0 + s1 identical). Also inits the atomic key array.
__device__ __forceinline__ void zsq2_body(const float* __restrict__ z,
                                          float* __restrict__ zsq,
                                          unsigned long long* __restrict__ key,
                                          int gid) {
    int q = gid >> 1, half = gid & 1;
    int b = q >> 10, t = q & 1023;
    const float* p = z + (size_t)b * (DD * 1024) + t + (size_t)(half * 128) * 1024;
    float s = 0.f;
    #pragma unroll 8
    for (int d = 0; d < 128; ++d) { float v = p[(size_t)d * 1024]; s = fmaf(v, v, s); }
    float so = __shfl_xor(s, 1, 64);             // partner half, same q
    if (half == 0) { zsq[q] = s + so; key[q] = ~0ull; }
}

// ---- fused prep: blocks [0,64) zsq+key | [64,320) B-coal | [320,576) A ----
__global__ void vq_prep_all(const float* __restrict__ z, const float* __restrict__ cb,
                            f16* __restrict__ Ah, f16* __restrict__ Al,
                            f16* __restrict__ Bh, f16* __restrict__ Bl,
                            float* __restrict__ zsq, unsigned long long* __restrict__ key) {
    __shared__ f16 Lh[32][DD + BP_PAD];
    __shared__ f16 Ll[32][DD + BP_PAD];
    int bid = blockIdx.x;
    int tid = threadIdx.x;
    if (bid < 64) {
        zsq2_body(z, zsq, key, bid * 256 + tid);
    } else if (bid < 320) {
        prep_b_coal(cb, Bh, Bl, 0, bid - 64, tid, Lh, Ll);
    } else {
        prep_a_vec_body(z, Ah, Al, bid - 320, tid);
    }
}

// standalone preps for the 2-pass fallback
__global__ void vq_prep_az(const float* __restrict__ z,
                           f16* __restrict__ Ah, f16* __restrict__ Al,
                           float* __restrict__ zsq, unsigned long long* __restrict__ key) {
    int bid = blockIdx.x;
    if (bid < 64) zsq2_body(z, zsq, key, bid * 256 + threadIdx.x);
    else          prep_a_vec_body(z, Ah, Al, bid - 64, threadIdx.x);
}
__global__ void vq_prep_b(const float* __restrict__ cb,
                          f16* __restrict__ Bh, f16* __restrict__ Bl, int kofs) {
    __shared__ f16 Lh[32][DD + BP_PAD];
    __shared__ f16 Ll[32][DD + BP_PAD];
    prep_b_coal(cb, Bh, Bl, kofs, blockIdx.x, threadIdx.x, Lh, Ll);
}

// 16 MFMAs of one term over the 4x4 accumulator tile
#define TERM16(AF, BF) do {                                                     \
    _Pragma("unroll") for (int _m = 0; _m < 4; ++_m)                            \
      _Pragma("unroll") for (int _n = 0; _n < 4; ++_n)                          \
        acc[_m][_n] = __builtin_amdgcn_mfma_f32_16x16x32_f16(                   \
            AF[_m], BF[_n], acc[_m][_n], 0, 0, 0);                              \
} while (0)

// ---- main GEMM (R27/R28-verbatim, NO setprio): 128x128 block, 2x2 waves of
//      64x64, A and B direct from global, NO barriers in the K-loop, T1/T3/T2
//      prefetch ping-pong, live fragments fixed at 16 x half8 (64 VGPR +
//      64 AGPR = exactly 4 blocks/CU). ----
__global__ __launch_bounds__(256, 4)
void vq_gemm16(const f16* __restrict__ Ah, const f16* __restrict__ Al,
               const f16* __restrict__ Bh, const f16* __restrict__ Bl,
               const float* __restrict__ zsq, unsigned long long* __restrict__ keyp,
               int kofs) {
    // Swizzle (R12/R21-verified): per XCD, 8-ntl B chunks x 8 mh2 A tiles.
    const int flat = blockIdx.x;
    const int xcd = flat & 7;
    const int idx = flat >> 3;
    const int mh2 = xcd * 8 + ((idx >> 3) & 7);     // 0..63, 128-row tile
    const int ntl = (idx >> 6) * 8 + (idx & 7);     // 0..63 / 0..31
    const int tid = threadIdx.x;
    const int lane = tid & 63;
    const int wv = tid >> 6;
    const int wm = wv >> 1, wn = wv & 1;            // 2x2 waves of 64x64
    const int quad = lane >> 4;
    const int l16 = lane & 15;

    __shared__ unsigned long long kbuf[256];        // epilogue merge only

    floatx4 acc[4][4];
    #pragma unroll
    for (int i = 0; i < 4; ++i)
        #pragma unroll
        for (int j = 0; j < 4; ++j) acc[i][j] = (floatx4)0.f;

    const int mt = mh2 >> 1;
    const int r0 = (mh2 & 1) * 128;
    // A fragment address in halfs (byte-identical granules to all passers):
    const size_t abase = ((((size_t)(mt * 8) * 4) + quad) * 256
                          + (size_t)(r0 + wm * 64 + l16)) * 8;
    const f16* Ap  = Ah + abase;
    const f16* Alp = Al + abase;
    const f16* Bpb = Bh + ((size_t)(ntl * 8) * 4 + quad) * 1024 + (size_t)(wn * 64 + l16) * 8;
    const f16* Blb = Bl + ((size_t)(ntl * 8) * 4 + quad) * 1024 + (size_t)(wn * 64 + l16) * 8;

    // Fragment slots: A0/A1 (A-side), B0/B1 (B-side). Even stage roles:
    // av=A0, aw=A1, bh=B0, bl=B1; odd stage: av=A1, aw=A0, bh=B0, bl=B1.
    half8 A0[4], A1[4], B0[4], B1[4];
    #pragma unroll
    for (int i = 0; i < 4; ++i) {
        A0[i] = *(const half8*)(Ap  + (size_t)i * 128);   // av(0)
        A1[i] = *(const half8*)(Alp + (size_t)i * 128);   // aw(0)
        B0[i] = *(const half8*)(Bpb + i * 128);           // bh(0)
        B1[i] = *(const half8*)(Blb + i * 128);           // bl(0)
    }

    #pragma unroll
    for (int su = 0; su < 4; ++su) {
        // ================= even stage s = 2*su =================
        TERM16(A0, B0);                              // T1: av*bh
        TERM16(A1, B0);                              // T3: aw*bh  (frees A1,B0)
        #pragma unroll
        for (int i = 0; i < 4; ++i) {                // prefetch av',bh'
            A1[i] = *(const half8*)(Ap  + 8192 + (size_t)i * 128);
            B0[i] = *(const half8*)(Bpb + 4096 + i * 128);
        }
        TERM16(A0, B1);                              // T2: av*bl  (frees A0,B1)
        #pragma unroll
        for (int i = 0; i < 4; ++i) {                // prefetch aw',bl'
            A0[i] = *(const half8*)(Alp + 8192 + (size_t)i * 128);
            B1[i] = *(const half8*)(Blb + 4096 + i * 128);
        }
        // ================= odd stage s = 2*su+1 (roles swapped) =================
        TERM16(A1, B0);                              // T1: av'*bh'
        TERM16(A0, B0);                              // T3: aw'*bh' (frees A0,B0)
        if (su < 3) {
            #pragma unroll
            for (int i = 0; i < 4; ++i) {            // prefetch av'',bh''
                A0[i] = *(const half8*)(Ap  + 16384 + (size_t)i * 128);
                B0[i] = *(const half8*)(Bpb + 8192 + i * 128);
            }
        }
        TERM16(A1, B1);                              // T2: av'*bl' (frees A1,B1)
        if (su < 3) {
            #pragma unroll
            for (int i = 0; i < 4; ++i) {            // prefetch aw'',bl''
                A1[i] = *(const half8*)(Alp + 16384 + (size_t)i * 128);
                B1[i] = *(const half8*)(Blb + 8192 + i * 128);
            }
            // advance two stages
            Ap += 16384; Alp += 16384; Bpb += 8192; Blb += 8192;
        }
    }

    // ---- epilogue (verified C/D map): dist quantization + 2-way merge +
    //      device-wide atomicMin (== sequential u64-min; ties impossible) ----
    const int kb = kofs + ntl * 128 + wn * 64;
    #pragma unroll
    for (int mi = 0; mi < 4; ++mi) {
        #pragma unroll
        for (int reg = 0; reg < 4; ++reg) {
            int qlocal = wm * 64 + mi * 16 + quad * 4 + reg;   // verified map
            float zq = zsq[mh2 * 128 + qlocal];
            float bd = FLT_MAX; int bk = 0;
            #pragma unroll
            for (int nj = 0; nj < 4; ++nj) {        // ascending k: '<' keeps lowest
                float dd = zq - acc[mi][nj][reg] * 0x1p-12f;  // single fp32 rounding
                int kk = kb + nj * 16 + l16;
                if (dd < bd || (dd == bd && kk < bk)) { bd = dd; bk = kk; }
            }
            #pragma unroll
            for (int mm = 1; mm <= 8; mm <<= 1) {   // 16-lane butterfly, same q
                float od = __shfl_xor(bd, mm, 64);
                int ok = __shfl_xor(bk, mm, 64);
                if (od < bd || (od == bd && ok < bk)) { bd = od; bk = ok; }
            }
            if (l16 == 0)
                kbuf[wn * 128 + qlocal] =
                    ((unsigned long long)__float_as_uint(bd) << 32) | (unsigned int)bk;
        }
    }
    __syncthreads();
    if (tid < 128) {
        unsigned long long k0 = kbuf[tid];
        unsigned long long k1 = kbuf[128 + tid];
        unsigned long long key = (k1 < k0) ? k1 : k0;
        atomicMin(&keyp[mh2 * 128 + tid], key);     // fire-and-forget, no fence
    }
}

__global__ void vq_extract(const unsigned long long* __restrict__ key,
                           int* __restrict__ out) {
    int q = blockIdx.x * 256 + threadIdx.x;
    out[q] = (int)(key[q] & 0xFFFFFFFFull);
}

extern "C" void kernel_launch(void* const* d_in, const int* in_sizes, int n_in,
                              void* d_out, int out_size, void* d_ws, size_t ws_size,
                              hipStream_t stream) {
    const float* z  = (const float*)d_in[0];   // (8, 256, 1024) fp32
    const float* cb = (const float*)d_in[1];   // (8192, 256) fp32
    char* ws = (char*)d_ws;
    f16* Ah = (f16*)(ws + WS_AH);
    f16* Al = (f16*)(ws + WS_AL);
    // zsq parked in d_out (32 KB): read by gemm, overwritten by extract.
    float* zsq = (float*)d_out;
    int* out = (int*)d_out;

    if (ws_size >= WS_NEED1) {
        f16* Bh = (f16*)(ws + WS_BH);
        f16* Bl = (f16*)(ws + WS_BL1);
        unsigned long long* key = (unsigned long long*)(ws + WS_KEY1);
        vq_prep_all<<<576, 256, 0, stream>>>(z, cb, Ah, Al, Bh, Bl, zsq, key);
        vq_gemm16<<<4096, 256, 0, stream>>>(Ah, Al, Bh, Bl, zsq, key, 0);
        vq_extract<<<NQ / 256, 256, 0, stream>>>(key, out);
    } else {
        // 2-pass fallback (12.06 MB): B buffer reused across halves of K.
        f16* Bh = (f16*)(ws + WS_BH);
        f16* Bl = (f16*)(ws + WS_BL2);
        unsigned long long* key = (unsigned long long*)(ws + WS_KEY2);
        vq_prep_az<<<320, 256, 0, stream>>>(z, Ah, Al, zsq, key);
        for (int p = 0; p < 2; ++p) {
            int kofs = p * 4096;
            vq_prep_b<<<128, 256, 0, stream>>>(cb, Bh, Bl, kofs);
            vq_gemm16<<<2048, 256, 0, stream>>>(Ah, Al, Bh, Bl, zsq, key, kofs);
        }
        vq_extract<<<NQ / 256, 256, 0, stream>>>(key, out);
    }
}